// Round 1
// baseline (850.112 us; speedup 1.0000x reference)
//
#include <hip/hip_runtime.h>
#include <hip/hip_bf16.h>
#include <math.h>

// Problem constants (fixed by the reference).
#define B_TOT 8192
#define E_    4
#define K_    16
#define D_    128
#define C_    512      // E*D
#define TB    16       // batch rows per block

// ---------------------------------------------------------------------------
// Kernel 0: collapse the two linears into one effective weight.
//   Weff[e*D+d, g] = sum_f W1[d,f] * W2[e*D+f, g]      (512 x 128)
//   beff[g]        = b2[g] + sum_c b1[c&127] * W2[c,g] (128)
// Then s = agg_flat @ Weff + beff exactly equals (agg@W1+b1) reshaped @ W2 + b2.
// ---------------------------------------------------------------------------
__global__ __launch_bounds__(128) void prep_weff(
    const float* __restrict__ W1, const float* __restrict__ b1,
    const float* __restrict__ W2, const float* __restrict__ b2,
    float* __restrict__ Weff, float* __restrict__ beff) {
  const int c = blockIdx.x;
  const int g = threadIdx.x;  // 0..127
  if (c < C_) {
    const int d = c & (D_ - 1);
    const int e = c >> 7;
    const float* __restrict__ w1row = W1 + d * D_;
    const float* __restrict__ w2blk = W2 + (e * D_) * D_;
    float acc = 0.f;
#pragma unroll 8
    for (int f = 0; f < D_; ++f) acc = fmaf(w1row[f], w2blk[f * D_ + g], acc);
    Weff[c * D_ + g] = acc;
  } else {
    float acc = b2[g];
    for (int cc = 0; cc < C_; ++cc)
      acc = fmaf(b1[cc & (D_ - 1)], W2[cc * D_ + g], acc);
    beff[g] = acc;
  }
}

// ---------------------------------------------------------------------------
// Main fused kernel: gather+mean -> LDS tile -> GEMM vs Weff -> dot -> sigmoid.
// Block: 256 threads (4 waves = 8 half-wave groups of 32), handles TB=16 rows.
// ---------------------------------------------------------------------------
__device__ __forceinline__ float sigf(float x) {
  return 1.f / (1.f + __expf(-x));
}

__global__ __launch_bounds__(256, 2) void hin2vec_main(
    const int* __restrict__ neighbors,   // [B,E,K]
    const int* __restrict__ end_node,    // [B]
    const int* __restrict__ path,        // [B]
    const float* __restrict__ emb_start, // [N,D]
    const float* __restrict__ emb_end,   // [N,D]
    const float* __restrict__ emb_path,  // [P,D]
    const float* __restrict__ Weff,      // [C,D]
    const float* __restrict__ beff,      // [D]
    float* __restrict__ out) {           // [B]
  __shared__ float agg_s[TB][C_];  // 32 KB: agg_flat tile, col c = e*128+d

  const int t   = threadIdx.x;
  const int b0  = blockIdx.x * TB;
  const int grp = t >> 5;   // half-wave group 0..7
  const int gl  = t & 31;   // lane within group

  // ---- Phase 1: gather & mean ------------------------------------------
  // 64 (lb,e) pairs per block; group handles pairs q = grp + 8*i.
  // Each pair: mean of K=16 rows of 128 floats; 32 lanes x float4 per row.
  for (int i = 0; i < 8; ++i) {
    const int q  = grp + (i << 3);
    const int lb = q >> 2;
    const int e  = q & 3;
    const int nbase = ((b0 + lb) * E_ + e) * K_;
    // lanes 0..15 (and 16..31, duplicated) each hold one neighbor index
    const int myidx = neighbors[nbase + (gl & 15)];
    float4 acc = make_float4(0.f, 0.f, 0.f, 0.f);
#pragma unroll
    for (int k = 0; k < K_; ++k) {
      const int idx = __shfl(myidx, k, 32);  // broadcast k-th index in group
      const float4 v =
          *(const float4*)(emb_start + (size_t)idx * D_ + gl * 4);
      acc.x += v.x; acc.y += v.y; acc.z += v.z; acc.w += v.w;
    }
    const float s = 1.f / 16.f;
    *(float4*)&agg_s[lb][e * D_ + gl * 4] =
        make_float4(acc.x * s, acc.y * s, acc.z * s, acc.w * s);
  }
  __syncthreads();

  // ---- Phase 2: s[r][:] = agg_s[r][:] @ Weff + beff --------------------
  // thread (tr=grp, tc=gl): rows {tr, tr+8}, cols tc*4..tc*4+3
  const int tc = gl;
  const int tr = grp;
  float acc0[4] = {0.f, 0.f, 0.f, 0.f};
  float acc1[4] = {0.f, 0.f, 0.f, 0.f};
  const float4* __restrict__ Wv = (const float4*)Weff;  // [512][32] of float4
#pragma unroll 4
  for (int k = 0; k < C_; ++k) {
    const float4 w = Wv[k * 32 + tc];
    const float a0 = agg_s[tr][k];       // broadcast within half-wave
    const float a1 = agg_s[tr + 8][k];
    acc0[0] = fmaf(a0, w.x, acc0[0]);
    acc0[1] = fmaf(a0, w.y, acc0[1]);
    acc0[2] = fmaf(a0, w.z, acc0[2]);
    acc0[3] = fmaf(a0, w.w, acc0[3]);
    acc1[0] = fmaf(a1, w.x, acc1[0]);
    acc1[1] = fmaf(a1, w.y, acc1[1]);
    acc1[2] = fmaf(a1, w.z, acc1[2]);
    acc1[3] = fmaf(a1, w.w, acc1[3]);
  }
  const float4 bev = ((const float4*)beff)[tc];
  acc0[0] += bev.x; acc0[1] += bev.y; acc0[2] += bev.z; acc0[3] += bev.w;
  acc1[0] += bev.x; acc1[1] += bev.y; acc1[2] += bev.z; acc1[3] += bev.w;

  // ---- Phase 3: out[b] = sigmoid( sum_g s[b,g] * e[b,g] * sig(p[b,g]) ) -
  const int br0 = b0 + tr;
  const int br1 = b0 + tr + 8;
  const float4 e0 = ((const float4*)(emb_end + (size_t)end_node[br0] * D_))[tc];
  const float4 e1 = ((const float4*)(emb_end + (size_t)end_node[br1] * D_))[tc];
  const float4 q0 = ((const float4*)(emb_path + path[br0] * D_))[tc];
  const float4 q1 = ((const float4*)(emb_path + path[br1] * D_))[tc];

  float p0 = acc0[0] * e0.x * sigf(q0.x) + acc0[1] * e0.y * sigf(q0.y) +
             acc0[2] * e0.z * sigf(q0.z) + acc0[3] * e0.w * sigf(q0.w);
  float p1 = acc1[0] * e1.x * sigf(q1.x) + acc1[1] * e1.y * sigf(q1.y) +
             acc1[2] * e1.z * sigf(q1.z) + acc1[3] * e1.w * sigf(q1.w);

#pragma unroll
  for (int off = 16; off; off >>= 1) {
    p0 += __shfl_xor(p0, off, 32);
    p1 += __shfl_xor(p1, off, 32);
  }
  if (gl == 0) {
    out[br0] = sigf(p0);
    out[br1] = sigf(p1);
  }
}

// ---------------------------------------------------------------------------
extern "C" void kernel_launch(void* const* d_in, const int* in_sizes, int n_in,
                              void* d_out, int out_size, void* d_ws,
                              size_t ws_size, hipStream_t stream) {
  const int*   neighbors = (const int*)  d_in[0];
  const int*   end_node  = (const int*)  d_in[1];
  const int*   path      = (const int*)  d_in[2];
  const float* emb_start = (const float*)d_in[3];
  const float* emb_end   = (const float*)d_in[4];
  const float* emb_path  = (const float*)d_in[5];
  const float* W1        = (const float*)d_in[6];
  const float* b1        = (const float*)d_in[7];
  const float* W2        = (const float*)d_in[8];
  const float* b2        = (const float*)d_in[9];
  float* out  = (float*)d_out;

  // Workspace: Weff (512*128 f32 = 256 KB) + beff (128 f32)
  float* Weff = (float*)d_ws;
  float* beff = Weff + C_ * D_;

  prep_weff<<<C_ + 1, D_, 0, stream>>>(W1, b1, W2, b2, Weff, beff);
  hin2vec_main<<<B_TOT / TB, 256, 0, stream>>>(
      neighbors, end_node, path, emb_start, emb_end, emb_path, Weff, beff, out);
}